// Round 1
// baseline (1061.766 us; speedup 1.0000x reference)
//
#include <hip/hip_runtime.h>
#include <stdint.h>

// Fused SortingModel kernel:
//   log_alpha = MLP(random)  (recomputed per block, tiny)
//   K = exp(log_alpha + gumbel)  stored bf16 in LDS, row-major AND transposed
//   20 multiplicative Sinkhorn iterations: a = 1/(K b), b = 1/(K^T a)
//   loss partial = sum_i (ordered[i] - b_i * (K^T (a*r))_i)^2, atomicAdd of mean
//
// Block = 1024 threads (16 waves), one block per matrix (2560 blocks).
// LDS: K (200x200 bf16, 400B lines) + KT + a[256] + b[256] + scr = 162,176 B.
// Each wave owns 13 lines (+1 duplicated boundary line, benign identical-value
// race); each 32-lane half processes one line per step: lanes 0..24 read one
// ds_read_b128 chunk (8 bf16), idle lanes' partials masked to 0, reduction via
// 4 DPP row_ror adds + shfl_xor(16) (VALU-dominant, DS pipe only for K reads).

#define NMAT 2560
#define NN 200
#define NU 32
#define NITER 20
#define LPW 13   // lines per wave (16*13 = 208 >= 200; extras read garbage, masked)
#define STEPS 7  // 2 lines per step per wave (one per 32-lane half)

// LDS layout in u32 units
#define K_OFF 0
#define KT_OFF 20000
#define A_OFF 40000
#define B_OFF 40256
#define SCR_OFF 40512
#define SM_U32 40544   // 162,176 bytes

__device__ __forceinline__ float blo(uint32_t u) { return __uint_as_float(u << 16); }
__device__ __forceinline__ float bhi(uint32_t u) { return __uint_as_float(u & 0xffff0000u); }

__device__ __forceinline__ uint32_t bpack(float lo, float hi) {
  // RNE bf16 pack of two finite floats into one dword (lo in [15:0])
  uint32_t a = __float_as_uint(lo); a += 0x7fffu + ((a >> 16) & 1u);
  uint32_t b = __float_as_uint(hi); b += 0x7fffu + ((b >> 16) & 1u);
  return (a >> 16) | (b & 0xffff0000u);
}

// Sum across each 32-lane half (caller must zero unwanted lanes' contributions).
// 4x DPP row_ror adds (within 16-lane rows, VALU pipe) + one shfl_xor(16).
__device__ __forceinline__ float halfsum(float x) {
  x += __int_as_float(__builtin_amdgcn_update_dpp(0, __float_as_int(x), 0x121, 0xf, 0xf, true));
  x += __int_as_float(__builtin_amdgcn_update_dpp(0, __float_as_int(x), 0x122, 0xf, 0xf, true));
  x += __int_as_float(__builtin_amdgcn_update_dpp(0, __float_as_int(x), 0x124, 0xf, 0xf, true));
  x += __int_as_float(__builtin_amdgcn_update_dpp(0, __float_as_int(x), 0x128, 0xf, 0xf, true));
  x += __shfl_xor(x, 16, 64);
  return x;
}

// One Sinkhorn half-iteration: vout[i] = 1 / sum_j mat[i][j] * vin[j]
// mat: bf16 lines of 100 u32 (200 elems); vin/vout: f32[256] in LDS.
__device__ __forceinline__ void sk_pass(const uint32_t* __restrict__ mat,
                                        const float* __restrict__ vin,
                                        float* __restrict__ vout,
                                        int wave, int hl, int half, bool act) {
  float vc[8];
  {
    const float4* vp = (const float4*)(vin + (hl << 3));
    float4 v0 = vp[0], v1 = vp[1];
    vc[0] = v0.x; vc[1] = v0.y; vc[2] = v0.z; vc[3] = v0.w;
    vc[4] = v1.x; vc[5] = v1.y; vc[6] = v1.z; vc[7] = v1.w;
  }
  const int base = wave * LPW + half;
#pragma unroll
  for (int s = 0; s < STEPS; ++s) {
    const int line = base + 2 * s;
    const uint4 k = *(const uint4*)(mat + line * 100 + (hl << 2));
    float acc;
    acc = blo(k.x) * vc[0];
    acc = fmaf(bhi(k.x), vc[1], acc);
    acc = fmaf(blo(k.y), vc[2], acc);
    acc = fmaf(bhi(k.y), vc[3], acc);
    acc = fmaf(blo(k.z), vc[4], acc);
    acc = fmaf(bhi(k.z), vc[5], acc);
    acc = fmaf(blo(k.w), vc[6], acc);
    acc = fmaf(bhi(k.w), vc[7], acc);
    acc = act ? acc : 0.0f;       // mask idle lanes (chunk >= 25) incl. NaN garbage
    const float t = halfsum(acc);
    if (hl == 0) vout[line] = __builtin_amdgcn_rcpf(t);
  }
}

__global__ void __launch_bounds__(1024)
sort_sinkhorn_kernel(const float* __restrict__ random_,     // [256*200]
                     const float* __restrict__ ordered_t,   // [2560*200]
                     const float* __restrict__ random_t,    // [2560*200]
                     const float* __restrict__ gumbel,      // [2560*200*200]
                     const float* __restrict__ W1,          // [32]
                     const float* __restrict__ b1,          // [32]
                     const float* __restrict__ W2,          // [200*32]
                     const float* __restrict__ b2,          // [200]
                     float* __restrict__ out) {
  extern __shared__ uint32_t sm[];
  uint32_t* K = sm + K_OFF;
  uint32_t* KT = sm + KT_OFF;
  float* av = (float*)(sm + A_OFF);
  float* bv = (float*)(sm + B_OFF);
  float* scr = (float*)(sm + SCR_OFF);

  const int tid = threadIdx.x;
  const int m = blockIdx.x;
  const int bidx = m & 255;          // tile index: log_alpha/random row block
  const int wave = tid >> 6;
  const int lane = tid & 63;
  const int half = lane >> 5;
  const int hl = lane & 31;
  const bool act = hl < 25;

  if (tid < 256) { bv[tid] = 1.0f; av[tid] = 1.0f; }

  // ---------------- build K = exp(MLP(random) + gumbel), bf16, K and K^T ----
  const size_t gbase = (size_t)m * (NN * NN);
  for (int t = tid; t < 2500; t += 1024) {
    const int ti = t / 50, tj = t % 50;
    const float4 rv = *(const float4*)(random_ + bidx * NN + 4 * ti);
    const float rr[4] = {rv.x, rv.y, rv.z, rv.w};
    float k16[16];
#pragma unroll
    for (int r = 0; r < 4; ++r) {
      float h[NU];
#pragma unroll
      for (int u = 0; u < NU; ++u)
        h[u] = fmaxf(0.0f, fmaf(rr[r], W1[u], b1[u]));
      const float4 gg = *(const float4*)(gumbel + gbase + (size_t)(4 * ti + r) * NN + 4 * tj);
      const float gga[4] = {gg.x, gg.y, gg.z, gg.w};
#pragma unroll
      for (int c = 0; c < 4; ++c) {
        float acc = b2[4 * tj + c];
        const float4* w4 = (const float4*)(W2 + (4 * tj + c) * NU);
#pragma unroll
        for (int q = 0; q < 8; ++q) {
          const float4 w = w4[q];
          acc = fmaf(h[4 * q + 0], w.x, acc);
          acc = fmaf(h[4 * q + 1], w.y, acc);
          acc = fmaf(h[4 * q + 2], w.z, acc);
          acc = fmaf(h[4 * q + 3], w.w, acc);
        }
        k16[r * 4 + c] = __expf(acc + gga[c]);
      }
    }
#pragma unroll
    for (int r = 0; r < 4; ++r) {
      uint2 w;
      w.x = bpack(k16[r * 4 + 0], k16[r * 4 + 1]);
      w.y = bpack(k16[r * 4 + 2], k16[r * 4 + 3]);
      *(uint2*)(K + (4 * ti + r) * 100 + tj * 2) = w;
    }
#pragma unroll
    for (int c = 0; c < 4; ++c) {
      uint2 w;
      w.x = bpack(k16[0 * 4 + c], k16[1 * 4 + c]);
      w.y = bpack(k16[2 * 4 + c], k16[3 * 4 + c]);
      *(uint2*)(KT + (4 * tj + c) * 100 + ti * 2) = w;
    }
  }
  __syncthreads();

  // ---------------- 20 multiplicative Sinkhorn iterations ------------------
  for (int it = 0; it < NITER; ++it) {
    sk_pass(K, bv, av, wave, hl, half, act);   // row normalize: a = 1/(K b)
    __syncthreads();
    sk_pass(KT, av, bv, wave, hl, half, act);  // col normalize: b = 1/(K^T a)
    __syncthreads();
  }

  // ---------------- loss: rec_i = b_i * (K^T (a .* r))_i --------------------
  float vc[8];
#pragma unroll
  for (int e = 0; e < 8; ++e) {
    const int j = (hl << 3) + e;
    vc[e] = (j < NN) ? av[j] * random_t[m * NN + j] : 0.0f;
  }
  float lacc = 0.0f;
  const int base = wave * LPW + half;
#pragma unroll
  for (int s = 0; s < STEPS; ++s) {
    const int line = base + 2 * s;
    const uint4 k = *(const uint4*)(KT + line * 100 + (hl << 2));
    float acc;
    acc = blo(k.x) * vc[0];
    acc = fmaf(bhi(k.x), vc[1], acc);
    acc = fmaf(blo(k.y), vc[2], acc);
    acc = fmaf(bhi(k.y), vc[3], acc);
    acc = fmaf(blo(k.z), vc[4], acc);
    acc = fmaf(bhi(k.z), vc[5], acc);
    acc = fmaf(blo(k.w), vc[6], acc);
    acc = fmaf(bhi(k.w), vc[7], acc);
    acc = act ? acc : 0.0f;
    const float t = halfsum(acc);
    const bool valid = (line < NN) && !(s == STEPS - 1 && half == 1);
    if (valid) {
      const float rec = bv[line] * t;
      const float o = ordered_t[m * NN + line];
      const float d = o - rec;
      lacc = fmaf(d, d, lacc);
    }
  }
  if (hl == 0) scr[wave * 2 + half] = lacc;
  __syncthreads();
  if (tid == 0) {
    float ssum = 0.0f;
#pragma unroll
    for (int i = 0; i < 32; ++i) ssum += scr[i];
    atomicAdd(out, ssum * (1.0f / 512000.0f));
  }
}

extern "C" void kernel_launch(void* const* d_in, const int* in_sizes, int n_in,
                              void* d_out, int out_size, void* d_ws, size_t ws_size,
                              hipStream_t stream) {
  (void)in_sizes; (void)n_in; (void)d_ws; (void)ws_size; (void)out_size;
  const float* random_  = (const float*)d_in[0];
  const float* ordered  = (const float*)d_in[1];
  const float* random_t = (const float*)d_in[2];
  const float* gumbel   = (const float*)d_in[3];
  const float* W1 = (const float*)d_in[4];
  const float* b1 = (const float*)d_in[5];
  const float* W2 = (const float*)d_in[6];
  const float* b2 = (const float*)d_in[7];
  float* out = (float*)d_out;

  const size_t smem = SM_U32 * sizeof(uint32_t);  // 162,176 B
  hipFuncSetAttribute((const void*)sort_sinkhorn_kernel,
                      hipFuncAttributeMaxDynamicSharedMemorySize, (int)smem);
  hipMemsetAsync(out, 0, sizeof(float), stream);  // harness poisons d_out once
  sort_sinkhorn_kernel<<<NMAT, 1024, smem, stream>>>(
      random_, ordered, random_t, gumbel, W1, b1, W2, b2, out);
}

// Round 2
// 764.730 us; speedup vs baseline: 1.3884x; 1.3884x over previous
//
#include <hip/hip_runtime.h>
#include <stdint.h>

// Register-resident Sinkhorn:
//   prep kernel: MLP relu(W1 x + b1) @ W2 + b2 is piecewise-AFFINE in scalar x
//     -> 33 interval coefficient rows (A,B) + 32 knots into d_ws.
//   main kernel: 1 block = 1 matrix, 320 threads (5 waves).
//     Thread (rg 0..39, cg 0..7) owns K tile rows [5rg..5rg+5) x cols
//     [base(cg)..base+csz) packed bf16 in 65 VGPRs (csz = 26/24, even bounds).
//     lane = cg(bits0-2) | (rg&7)(bits3-5), wave = rg>>3.
//   Row pass  a_i = 1/(K b)_i  : per-row MAC over 26 cols, reduce over cg via
//     quad_perm xor1/xor2 + ds_swizzle xor4 (1 LDS op per row).
//   Col pass  b_j = 1/(K^T a)_j: per-col MAC over 5 rows, reduce over rg-in-wave
//     ALL-VALU (row_ror:8 + permlane16_swap + permlane32_swap), 8 lanes/wave
//     write wave-partials to LDS scr; 100 pair-threads combine 5 waves + rcp.
//   Loss: col pass with (a .* r), rec = b * sum, mean((ordered-rec)^2).

#define NN 200
#define NMAT 2560
#define NITER 20

typedef uint32_t u32;

__device__ __forceinline__ float blo(u32 u){ return __uint_as_float(u<<16); }
__device__ __forceinline__ float bhi(u32 u){ return __uint_as_float(u & 0xffff0000u); }
__device__ __forceinline__ u32 bpack(float lo, float hi){
  u32 a=__float_as_uint(lo); a += 0x7fffu + ((a>>16)&1u);
  u32 b=__float_as_uint(hi); b += 0x7fffu + ((b>>16)&1u);
  return (a>>16) | (b & 0xffff0000u);
}

template<int CTRL>
__device__ __forceinline__ float dpp_add(float x){
  return x + __int_as_float(__builtin_amdgcn_update_dpp(0, __float_as_int(x), CTRL, 0xF, 0xF, true));
}
template<int PAT>
__device__ __forceinline__ float swz_add(float x){
  return x + __int_as_float(__builtin_amdgcn_ds_swizzle(__float_as_int(x), PAT));
}
__device__ __forceinline__ float pl16_add(float x){
#if __has_builtin(__builtin_amdgcn_permlane16_swap)
  auto r = __builtin_amdgcn_permlane16_swap(__float_as_uint(x), __float_as_uint(x), false, false);
  return __uint_as_float(r[0]) + __uint_as_float(r[1]);
#else
  return x + __shfl_xor(x, 16, 64);
#endif
}
__device__ __forceinline__ float pl32_add(float x){
#if __has_builtin(__builtin_amdgcn_permlane32_swap)
  auto r = __builtin_amdgcn_permlane32_swap(__float_as_uint(x), __float_as_uint(x), false, false);
  return __uint_as_float(r[0]) + __uint_as_float(r[1]);
#else
  return x + __shfl_xor(x, 32, 64);
#endif
}

// ---------------- prep: piecewise-affine MLP coefficients ------------------
// ws layout (f32): [0..32) knots (unsorted); [32..32+6600) A[33][200];
//                  [6632..6632+6600) B[33][200].  Total 52,928 bytes.
__global__ void __launch_bounds__(256)
prep_kernel(const float* __restrict__ W1, const float* __restrict__ b1,
            const float* __restrict__ W2, const float* __restrict__ b2,
            float* __restrict__ ws) {
  __shared__ float kn[32], sg[32], w1s[32], b1s[32];
  __shared__ int ord[32];
  const int tid = threadIdx.x;
  if (tid < 32) {
    const float w1 = W1[tid], bv = b1[tid];
    float knot, s;
    if (w1 != 0.f) { knot = -bv / w1; s = (w1 > 0.f) ? 1.f : -1.f; }
    else           { knot = (bv > 0.f) ? -1e30f : 1e30f; s = 1.f; }
    kn[tid] = knot; sg[tid] = s; w1s[tid] = w1; b1s[tid] = bv;
    ws[tid] = knot;
  }
  __syncthreads();
  if (tid < 32) {
    int rk = 0;
#pragma unroll
    for (int v = 0; v < 32; ++v) {
      const float kv = kn[v];
      rk += (kv < kn[tid] || (kv == kn[tid] && v < tid)) ? 1 : 0;
    }
    ord[rk] = tid;
  }
  __syncthreads();
  if (tid < NN) {
    float w2l[32];
#pragma unroll
    for (int u = 0; u < 32; ++u) w2l[u] = W2[tid*32 + u];
    float A = 0.f, Bv = b2[tid];
#pragma unroll
    for (int u = 0; u < 32; ++u)
      if (sg[u] < 0.f) { A += w2l[u]*w1s[u]; Bv += w2l[u]*b1s[u]; }
    float* At = ws + 32;
    float* Bt = ws + 32 + 33*NN;
    At[tid] = A; Bt[tid] = Bv;
    for (int s = 0; s < 32; ++s) {
      const int u = ord[s];
      A  += sg[u]*w2l[u]*w1s[u];
      Bv += sg[u]*w2l[u]*b1s[u];
      At[(s+1)*NN + tid] = A;
      Bt[(s+1)*NN + tid] = Bv;
    }
  }
}

// ---------------- main ------------------------------------------------------
__global__ void __launch_bounds__(320)
sinkhorn_main(const float* __restrict__ random_,    // [256*200]
              const float* __restrict__ ordered_t,  // [2560*200]
              const float* __restrict__ random_t,   // [2560*200]
              const float* __restrict__ gumbel,     // [2560*200*200]
              const float* __restrict__ ws,
              float* __restrict__ out) {
  __shared__ float scr[5*8*26];   // [wave][cg][k] col-pass wave partials
  __shared__ float bb[208];       // b vector f32 (+8 pad, init 1.0)

  const int tid  = threadIdx.x;
  const int m    = blockIdx.x;
  const int bidx = m & 255;
  const int w    = tid >> 6;
  const int lane = tid & 63;
  const int cg   = lane & 7;          // bits 0-2
  const int rgl  = (lane >> 3) & 7;   // bits 3-5
  const int rg   = w * 8 + rgl;       // 0..39, rows [5rg, 5rg+5)
  const int cbase = 25*cg + (cg & 1); // {0,26,50,76,100,126,150,176}
  const int csz   = 26 - 2*(cg & 1);  // 26 even cg, 24 odd cg

  if (tid < 208) bb[tid] = 1.0f;

  const float* knots = ws;
  const float* At = ws + 32;
  const float* Bt = ws + 32 + 33*NN;

  // pair-thread mapping (tid<100): cols (2p, 2p+1) -> (cg, k even)
  const bool isp = (tid < 100);
  int pcg = 0, pk = 0;
  if (isp) {
    const int q = tid / 25, rem = tid - 25*q;
    if (rem < 13) { pcg = 2*q;     pk = 2*rem;        }
    else          { pcg = 2*q + 1; pk = 2*(rem - 13); }
  }
  const int pscr = pcg*26 + pk;

  // ------- build K tile: exp(A[idx]*x + B[idx] + gumbel), packed bf16 -------
  u32 Kt[5][13];
  float xr[5], rt[5];
  int ii[5];
  const size_t gb = (size_t)m * (NN*NN);

#pragma unroll
  for (int r = 0; r < 5; ++r) {
    const int row = rg*5 + r;
    xr[r] = random_[bidx*NN + row];
    rt[r] = random_t[m*NN + row];
    int c = 0;
#pragma unroll
    for (int u = 0; u < 32; ++u) c += (knots[u] < xr[r]) ? 1 : 0;
    ii[r] = c;
  }
#pragma unroll
  for (int r = 0; r < 5; ++r) {
    const int row = rg*5 + r;
    const float* Ar = At + ii[r]*NN + cbase;
    const float* Br = Bt + ii[r]*NN + cbase;
    const float* gr = gumbel + gb + (size_t)row*NN + cbase;
#pragma unroll
    for (int k = 0; k < 13; ++k) {
      u32 pkd = 0;
      if (2*k < csz) {   // k==12 only valid for even cg (guards OOB too)
        const float2 av = *(const float2*)(Ar + 2*k);
        const float2 bv = *(const float2*)(Br + 2*k);
        const float2 gv = *(const float2*)(gr + 2*k);
        const float e0 = __expf(fmaf(xr[r], av.x, bv.x) + gv.x);
        const float e1 = __expf(fmaf(xr[r], av.y, bv.y) + gv.y);
        pkd = bpack(e0, e1);
      }
      Kt[r][k] = pkd;
    }
  }
  __syncthreads();

  // ------- 20 multiplicative Sinkhorn iterations ---------------------------
  float a[5];
  float b0r = 1.f, b1r = 1.f;   // persistent per pair-thread

  for (int it = 0; it < NITER; ++it) {
    // row pass: a = 1/(K b)
    float bl[26];
#pragma unroll
    for (int k = 0; k < 13; ++k) {
      const float2 v = *(const float2*)(bb + cbase + 2*k);
      bl[2*k] = v.x; bl[2*k+1] = v.y;
    }
#pragma unroll
    for (int r = 0; r < 5; ++r) {
      float acc = 0.f;
#pragma unroll
      for (int k = 0; k < 13; ++k) {
        const u32 d = Kt[r][k];
        acc = fmaf(blo(d), bl[2*k],   acc);
        acc = fmaf(bhi(d), bl[2*k+1], acc);
      }
      acc = dpp_add<0xB1>(acc);    // xor1 (quad_perm 1,0,3,2)
      acc = dpp_add<0x4E>(acc);    // xor2 (quad_perm 2,3,0,1)
      acc = swz_add<0x101F>(acc);  // xor4 (ds_swizzle)
      a[r] = __builtin_amdgcn_rcpf(acc);
    }
    // col pass: b = 1/(K^T a)
#pragma unroll
    for (int k = 0; k < 26; ++k) {
      float acc = 0.f;
#pragma unroll
      for (int r = 0; r < 5; ++r) {
        const u32 d = Kt[r][k>>1];
        const float kv = (k & 1) ? bhi(d) : blo(d);
        acc = fmaf(kv, a[r], acc);
      }
      acc = dpp_add<0x128>(acc);   // xor8 (row_ror:8)
      acc = pl16_add(acc);         // xor16
      acc = pl32_add(acc);         // xor32
      if ((lane & 56) == 0) scr[w*208 + cg*26 + k] = acc;
    }
    __syncthreads();
    if (isp) {
      float s0 = 0.f, s1 = 0.f;
#pragma unroll
      for (int ww = 0; ww < 5; ++ww) {
        const float2 v = *(const float2*)(scr + ww*208 + pscr);
        s0 += v.x; s1 += v.y;
      }
      b0r = __builtin_amdgcn_rcpf(s0);
      b1r = __builtin_amdgcn_rcpf(s1);
      *(float2*)(bb + 2*tid) = make_float2(b0r, b1r);
    }
    __syncthreads();
  }

  // ------- loss: rec = b .* K^T(a .* r); mean((ordered - rec)^2) -----------
  float ar[5];
#pragma unroll
  for (int r = 0; r < 5; ++r) ar[r] = a[r] * rt[r];
#pragma unroll
  for (int k = 0; k < 26; ++k) {
    float acc = 0.f;
#pragma unroll
    for (int r = 0; r < 5; ++r) {
      const u32 d = Kt[r][k>>1];
      const float kv = (k & 1) ? bhi(d) : blo(d);
      acc = fmaf(kv, ar[r], acc);
    }
    acc = dpp_add<0x128>(acc);
    acc = pl16_add(acc);
    acc = pl32_add(acc);
    if ((lane & 56) == 0) scr[w*208 + cg*26 + k] = acc;
  }
  __syncthreads();
  float lacc = 0.f;
  if (isp) {
    float s0 = 0.f, s1 = 0.f;
#pragma unroll
    for (int ww = 0; ww < 5; ++ww) {
      const float2 v = *(const float2*)(scr + ww*208 + pscr);
      s0 += v.x; s1 += v.y;
    }
    const float2 ov = *(const float2*)(ordered_t + m*NN + 2*tid);
    const float d0 = ov.x - b0r*s0;
    const float d1 = ov.y - b1r*s1;
    lacc = fmaf(d0, d0, d1*d1);
  }
  if (w < 2) {
    lacc = dpp_add<0xB1>(lacc);
    lacc = dpp_add<0x4E>(lacc);
    lacc = swz_add<0x101F>(lacc);
    lacc = dpp_add<0x128>(lacc);
    lacc = pl16_add(lacc);
    lacc = pl32_add(lacc);
    if (lane == 0) bb[w] = lacc;
  }
  __syncthreads();
  if (tid == 0) atomicAdd(out, (bb[0] + bb[1]) * (1.0f / 512000.0f));
}

extern "C" void kernel_launch(void* const* d_in, const int* in_sizes, int n_in,
                              void* d_out, int out_size, void* d_ws, size_t ws_size,
                              hipStream_t stream) {
  (void)in_sizes; (void)n_in; (void)ws_size; (void)out_size;
  const float* random_  = (const float*)d_in[0];
  const float* ordered  = (const float*)d_in[1];
  const float* random_t = (const float*)d_in[2];
  const float* gumbel   = (const float*)d_in[3];
  const float* W1 = (const float*)d_in[4];
  const float* b1 = (const float*)d_in[5];
  const float* W2 = (const float*)d_in[6];
  const float* b2 = (const float*)d_in[7];
  float* out = (float*)d_out;
  float* ws  = (float*)d_ws;   // needs 52,928 B

  prep_kernel<<<1, 256, 0, stream>>>(W1, b1, W2, b2, ws);
  hipMemsetAsync(out, 0, sizeof(float), stream);
  sinkhorn_main<<<NMAT, 320, 0, stream>>>(random_, ordered, random_t, gumbel, ws, out);
}